// Round 12
// baseline (174.531 us; speedup 1.0000x reference)
//
#include <hip/hip_runtime.h>
#include <math.h>

#define BB    4
#define TT    1024
#define DD    512
#define NH    8
#define DH    64
#define BH    32          // BB*NH
#define INV_TAU 10.0f

typedef __attribute__((ext_vector_type(8))) short short8;
typedef __attribute__((ext_vector_type(4))) float f4;
typedef __attribute__((ext_vector_type(8))) _Float16 half8;
typedef __attribute__((ext_vector_type(4))) _Float16 half4v;
typedef __attribute__((ext_vector_type(2))) _Float16 half2v;

typedef __attribute__((address_space(3))) unsigned int lds_u32;
typedef __attribute__((address_space(1))) const unsigned short glob_u16;

__device__ inline unsigned short f2bf(float f) {
  unsigned u = __float_as_uint(f);
  u += 0x7FFFu + ((u >> 16) & 1u);        // round-to-nearest-even
  return (unsigned short)(u >> 16);
}
__device__ inline float bf2f(unsigned short h) {
  return __uint_as_float(((unsigned)h) << 16);
}

// ---------------------------------------------------------------------------
// K0 "prep": merged split_x (blocks 0..2047) + split_wt (blocks 2048..2239).
// ---------------------------------------------------------------------------
__global__ __launch_bounds__(256) void k_prep(
    const float* __restrict__ x, const float* __restrict__ wq,
    const float* __restrict__ wk, const float* __restrict__ wv,
    unsigned short* __restrict__ xh, unsigned short* __restrict__ xl,
    unsigned short* __restrict__ wth, unsigned short* __restrict__ wtl)
{
  __shared__ float Wf[64][65];
  const int blk = blockIdx.x;
  const int tid = threadIdx.x;
  if (blk < 2048) {
    const int i = (blk * 256 + tid) * 4;
    float4 v = *(const float4*)&x[i];
    ushort4 h, l;
    h.x = f2bf(v.x); l.x = f2bf(v.x - bf2f(h.x));
    h.y = f2bf(v.y); l.y = f2bf(v.y - bf2f(h.y));
    h.z = f2bf(v.z); l.z = f2bf(v.z - bf2f(h.z));
    h.w = f2bf(v.w); l.w = f2bf(v.w - bf2f(h.w));
    *(ushort4*)&xh[i] = h;
    *(ushort4*)&xl[i] = l;
    return;
  }
  const int b = blk - 2048;                // 0..191
  const int ten = b >> 6;                  // 0..2
  const int r = b & 63;
  const int n0 = (r & 7) * 64, k0 = (r >> 3) * 64;
  const float* W = (ten == 0) ? wq : ((ten == 1) ? wk : wv);
#pragma unroll
  for (int p = 0; p < 4; ++p) {
    int kk = p * 16 + (tid >> 4);
    int nn = (tid & 15) * 4;
    float4 v = *(const float4*)&W[(size_t)(k0 + kk) * 512 + n0 + nn];
    Wf[kk][nn + 0] = v.x; Wf[kk][nn + 1] = v.y;
    Wf[kk][nn + 2] = v.z; Wf[kk][nn + 3] = v.w;
  }
  __syncthreads();
  const int n = tid >> 2, kq = tid & 3;
  size_t base = ((size_t)(ten * 512 + n0 + n)) * 512 + k0 + kq * 16;
#pragma unroll
  for (int jj = 0; jj < 4; ++jj) {
    ushort4 h, l;
    float f0 = Wf[kq * 16 + jj * 4 + 0][n];
    float f1 = Wf[kq * 16 + jj * 4 + 1][n];
    float f2 = Wf[kq * 16 + jj * 4 + 2][n];
    float f3 = Wf[kq * 16 + jj * 4 + 3][n];
    h.x = f2bf(f0); l.x = f2bf(f0 - bf2f(h.x));
    h.y = f2bf(f1); l.y = f2bf(f1 - bf2f(h.y));
    h.z = f2bf(f2); l.z = f2bf(f2 - bf2f(h.z));
    h.w = f2bf(f3); l.w = f2bf(f3 - bf2f(h.w));
    *(ushort4*)&wth[base + jj * 4] = h;
    *(ushort4*)&wtl[base + jj * 4] = l;
  }
}

// ---------------------------------------------------------------------------
// K1: QKV projection via bf16x3 MFMA + fused per-head softmax.
// Staging via global_load_lds width=16 into linear LDS [R][32] with the
// both-sides XOR chunk swizzle (round-10, verified bit-identical).
// Epilogue: Q fp16, K fp16 hi+lo, V fp16 row-major (vsh) — fp16 conversion
// at the source is bitwise-identical to the old fp32 round-trip, saves
// 6MB write + 6MB read on the V path.
// ---------------------------------------------------------------------------
__global__ __launch_bounds__(256) void k_proj_mfma(
    const unsigned short* __restrict__ xh, const unsigned short* __restrict__ xl,
    const unsigned short* __restrict__ wth, const unsigned short* __restrict__ wtl,
    _Float16* __restrict__ qh, _Float16* __restrict__ kh,
    _Float16* __restrict__ kl, _Float16* __restrict__ vsh)
{
  __shared__ unsigned short Ah[64][32];
  __shared__ unsigned short Al[64][32];
  __shared__ unsigned short Bh[128][32];
  __shared__ unsigned short Bl[128][32];
  const int tid = threadIdx.x;
  const int n0g = blockIdx.x * 128;        // 0..1408
  const int m0 = blockIdx.y * 64;          // 0..4032
  const int w = tid >> 6, lane = tid & 63;
  const int mw = (w & 1) * 32, nw = (w >> 1) * 64;
  const int quad = lane >> 4, l16 = lane & 15;

  const int rl = lane >> 2;
  const int swz = ((lane & 3) ^ (rl & 3)) * 8;  // fetched chunk, elements

  f4 acc[2][4] = {};

  for (int k0 = 0; k0 < DD; k0 += 32) {
    {
      size_t src = (size_t)(m0 + w * 16 + rl) * DD + k0 + swz;
      __builtin_amdgcn_global_load_lds((glob_u16*)&xh[src],
                                       (lds_u32*)&Ah[w * 16][0], 16, 0, 0);
      __builtin_amdgcn_global_load_lds((glob_u16*)&xl[src],
                                       (lds_u32*)&Al[w * 16][0], 16, 0, 0);
    }
    {
      size_t s0 = (size_t)(n0g + w * 32 + rl) * DD + k0 + swz;
      size_t s1 = (size_t)(n0g + w * 32 + 16 + rl) * DD + k0 + swz;
      __builtin_amdgcn_global_load_lds((glob_u16*)&wth[s0],
                                       (lds_u32*)&Bh[w * 32][0], 16, 0, 0);
      __builtin_amdgcn_global_load_lds((glob_u16*)&wth[s1],
                                       (lds_u32*)&Bh[w * 32 + 16][0], 16, 0, 0);
      __builtin_amdgcn_global_load_lds((glob_u16*)&wtl[s0],
                                       (lds_u32*)&Bl[w * 32][0], 16, 0, 0);
      __builtin_amdgcn_global_load_lds((glob_u16*)&wtl[s1],
                                       (lds_u32*)&Bl[w * 32 + 16][0], 16, 0, 0);
    }
    __syncthreads();                       // drains vmcnt before barrier

    short8 fbh[4], fbl[4];
#pragma unroll
    for (int nt = 0; nt < 4; ++nt) {
      int rb = nw + nt * 16 + l16;
      int cb = ((quad ^ (rb & 3)) * 8);
      fbh[nt] = *(const short8*)&Bh[rb][cb];
      fbl[nt] = *(const short8*)&Bl[rb][cb];
    }
#pragma unroll
    for (int mt = 0; mt < 2; ++mt) {
      int ra = mw + mt * 16 + l16;
      int ca = ((quad ^ (ra & 3)) * 8);
      short8 fah = *(const short8*)&Ah[ra][ca];
      short8 fal = *(const short8*)&Al[ra][ca];
#pragma unroll
      for (int nt = 0; nt < 4; ++nt) {
        acc[mt][nt] = __builtin_amdgcn_mfma_f32_16x16x32_bf16(fah, fbh[nt], acc[mt][nt], 0, 0, 0);
        acc[mt][nt] = __builtin_amdgcn_mfma_f32_16x16x32_bf16(fah, fbl[nt], acc[mt][nt], 0, 0, 0);
        acc[mt][nt] = __builtin_amdgcn_mfma_f32_16x16x32_bf16(fal, fbh[nt], acc[mt][nt], 0, 0, 0);
      }
    }
    __syncthreads();
  }

  const int tensor = n0g >> 9;
  const int ncol = (n0g & 511) + nw;
  const int h = ncol >> 6;
#pragma unroll
  for (int mt = 0; mt < 2; ++mt) {
#pragma unroll
    for (int r = 0; r < 4; ++r) {
      float v0 = acc[mt][0][r], v1 = acc[mt][1][r];
      float v2 = acc[mt][2][r], v3 = acc[mt][3][r];
      float mx = fmaxf(fmaxf(v0, v1), fmaxf(v2, v3));
#pragma unroll
      for (int msk = 1; msk <= 8; msk <<= 1) mx = fmaxf(mx, __shfl_xor(mx, msk, 64));
      float e0 = __expf((v0 - mx) * INV_TAU);
      float e1 = __expf((v1 - mx) * INV_TAU);
      float e2 = __expf((v2 - mx) * INV_TAU);
      float e3 = __expf((v3 - mx) * INV_TAU);
      float sm = (e0 + e1) + (e2 + e3);
#pragma unroll
      for (int msk = 1; msk <= 8; msk <<= 1) sm += __shfl_xor(sm, msk, 64);
      float inv = 1.0f / sm;
      int row = m0 + mw + mt * 16 + quad * 4 + r;
      int b = row >> 10, t = row & 1023;
      size_t base = (((size_t)b * NH + h) * TT + t) * DH;
      float e[4] = {e0 * inv, e1 * inv, e2 * inv, e3 * inv};
      if (tensor == 2) {
#pragma unroll
        for (int c = 0; c < 4; ++c) vsh[base + l16 + c * 16] = (_Float16)e[c];
      } else if (tensor == 0) {
#pragma unroll
        for (int c = 0; c < 4; ++c) qh[base + l16 + c * 16] = (_Float16)e[c];
      } else {
#pragma unroll
        for (int c = 0; c < 4; ++c) {
          _Float16 hh = (_Float16)e[c];
          kh[base + l16 + c * 16] = hh;
          kl[base + l16 + c * 16] = (_Float16)(e[c] - (float)hh);
        }
      }
    }
  }
}

// ---------------------------------------------------------------------------
// K2 "qkv": merged qk (blocks 0..1087) + vsplit (blocks 1088..1599).
// QK^T in fp16, 2 terms: A = qh*(kh+kl) (round-9 verified). vsplit now
// reads fp16 V (2MB instead of 8MB fp32) and emits V^T fp16.
// ---------------------------------------------------------------------------
__global__ __launch_bounds__(256) void k_qkv(
    const _Float16* __restrict__ qh, const _Float16* __restrict__ kh,
    const _Float16* __restrict__ kl, _Float16* __restrict__ A,
    const _Float16* __restrict__ vsh, _Float16* __restrict__ vth)
{
  __shared__ float Vf[64][65];
  const int tid = threadIdx.x;
  if (blockIdx.x >= 1088) {
    const int b = blockIdx.x - 1088;       // 0..511
    const int z = b & 31, t0 = (b >> 5) * 64;
#pragma unroll
    for (int it = 0; it < 4; ++it) {
      int tl = it * 16 + (tid >> 4);
      int d4 = (tid & 15) * 4;
      half4v v = *(const half4v*)&vsh[((size_t)z * TT + t0 + tl) * DH + d4];
      Vf[tl][d4 + 0] = (float)v[0]; Vf[tl][d4 + 1] = (float)v[1];
      Vf[tl][d4 + 2] = (float)v[2]; Vf[tl][d4 + 3] = (float)v[3];
    }
    __syncthreads();
#pragma unroll
    for (int it = 0; it < 8; ++it) {
      int d = it * 8 + (tid >> 5);
      int t = (tid & 31) * 2;
      half2v hh;
      hh[0] = (_Float16)Vf[t][d];
      hh[1] = (_Float16)Vf[t + 1][d];
      *(half2v*)&vth[((size_t)z * DH + d) * TT + t0 + t] = hh;
    }
    return;
  }
  const int gid = blockIdx.x * 4 + (tid >> 6);
  const int z = gid / 136;
  const int lx = gid - z * 136;
  int ti = (int)((sqrtf(8.0f * lx + 1.0f) - 1.0f) * 0.5f);
  while ((ti + 1) * (ti + 2) / 2 <= lx) ++ti;
  while (ti * (ti + 1) / 2 > lx) --ti;
  const int tj = lx - ti * (ti + 1) / 2;
  const int i0 = ti * 64, j0 = tj * 64;
  const int lane = tid & 63;
  const int quad = lane >> 4, l16 = lane & 15;
  const size_t zb = (size_t)z * TT * DH;

  half8 fbh[4][2], fbl[4][2];
#pragma unroll
  for (int nt = 0; nt < 4; ++nt)
#pragma unroll
    for (int ks = 0; ks < 2; ++ks) {
      size_t o = zb + (size_t)(j0 + nt * 16 + l16) * DH + ks * 32 + quad * 8;
      fbh[nt][ks] = *(const half8*)&kh[o];
      fbl[nt][ks] = *(const half8*)&kl[o];
    }

  f4 acc[4][4] = {};
#pragma unroll
  for (int mt = 0; mt < 4; ++mt) {
    half8 fah[2];
#pragma unroll
    for (int ks = 0; ks < 2; ++ks) {
      size_t o = zb + (size_t)(i0 + mt * 16 + l16) * DH + ks * 32 + quad * 8;
      fah[ks] = *(const half8*)&qh[o];
    }
#pragma unroll
    for (int nt = 0; nt < 4; ++nt)
#pragma unroll
      for (int ks = 0; ks < 2; ++ks) {
        acc[mt][nt] = __builtin_amdgcn_mfma_f32_16x16x32_f16(fah[ks], fbh[nt][ks], acc[mt][nt], 0, 0, 0);
        acc[mt][nt] = __builtin_amdgcn_mfma_f32_16x16x32_f16(fah[ks], fbl[nt][ks], acc[mt][nt], 0, 0, 0);
      }
  }

  _Float16* Ab = A + (size_t)z * TT * TT;
#pragma unroll
  for (int mt = 0; mt < 4; ++mt)
#pragma unroll
    for (int nt = 0; nt < 4; ++nt)
#pragma unroll
      for (int r = 0; r < 4; ++r)
        Ab[(size_t)(i0 + mt * 16 + quad * 4 + r) * TT + j0 + nt * 16 + l16] =
            (_Float16)acc[mt][nt][r];
}

// ---------------------------------------------------------------------------
// K3: diagonal run-length scan — single global read + single global write.
// Phase A fuses staging with HALF-sums (S0 kept in-register); phase B runs
// two independent prefix/max chains over the chunk halves (depth Ls/2,
// merged once at the end). Ls is even for every band. Phase C stays serial
// (its running max feeds each output). St[512][64] fp16 = 64KB.
// ---------------------------------------------------------------------------
__global__ __launch_bounds__(1024) void k_scan(_Float16* __restrict__ A)
{
  __shared__ _Float16 St[512][64];         // 64 KB band staging
  __shared__ float Ssum[16][64];
  __shared__ float Gmax[16][64];
  const int blk = blockIdx.x;              // 0..511
  const int p = blk >> 5;                  // 0..15
  const int xb = (p < 8) ? p : (23 - p);   // complementary pairing across CUs
  const int z = blk & 31;
  const int lane = threadIdx.x & 63;
  const int w = threadIdx.x >> 6;          // wave 0..15
  _Float16* __restrict__ Ab = A + (size_t)z * TT * TT;
  const int dbase = xb * 64;
  const int d = dbase + lane;              // this lane's diagonal
  const int R = TT - dbase;                // rows in this diagonal band
  const int nseg = (R > 512) ? 2 : 1;
  const int Rseg = R / nseg;               // <= 512 rows per segment
  const int Ls = Rseg >> 4;                // rows per wave-chunk (even)

  float cs_carry = 0.0f, m_carry = 0.0f;
  for (int sg = 0; sg < nseg; ++sg) {
    const int rbase = dbase + sg * Rseg;
    const int t0 = w * Ls;
    const int H = Ls >> 1;

    // Phase A: stage + fused HALF sums (two independent chains).
    float S0 = 0.0f, S1 = 0.0f;
    for (int t = 0; t < H; ++t) {
      int ia = rbase + t0 + t;
      int ib = ia + H;
      float sa = (float)Ab[ia * (TT + 1) - d];
      float sb = (float)Ab[ib * (TT + 1) - d];
      float a0 = (ia >= d) ? sa : 0.0f;
      float a1 = (ib >= d) ? sb : 0.0f;
      St[t0 + t][lane] = (_Float16)a0;
      St[t0 + H + t][lane] = (_Float16)a1;
      S0 += a0;
      S1 += a1;
    }
    Ssum[w][lane] = S0 + S1;
    __syncthreads();

    float cs_in = cs_carry;
    float tot = cs_carry;
    for (int ww = 0; ww < 16; ++ww) {
      float sv = Ssum[ww][lane];
      cs_in += (ww < w) ? sv : 0.0f;
      tot += sv;
    }

    // Phase B: two independent prefix/max chains over the chunk halves.
    {
      float lcs0 = 0.0f, lcs1 = S0, gm0 = 0.0f, gm1 = 0.0f;
#pragma unroll 4
      for (int t = 0; t < H; ++t) {
        float s0 = (float)St[t0 + t][lane];
        float s1 = (float)St[t0 + H + t][lane];
        lcs0 += s0;
        lcs1 += s1;
        gm0 = fmaxf(gm0, (cs_in + lcs0) * (1.0f - s0));
        gm1 = fmaxf(gm1, (cs_in + lcs1) * (1.0f - s1));
      }
      Gmax[w][lane] = fmaxf(gm0, gm1);
    }
    __syncthreads();

    float m = m_carry;
    float mtot = m_carry;
    for (int ww = 0; ww < 16; ++ww) {
      float gv = Gmax[ww][lane];
      m = fmaxf(m, (ww < w) ? gv : 0.0f);  // values are >= 0
      mtot = fmaxf(mtot, gv);
    }

    // Phase C: finalize, single coalesced global write (serial by nature).
    {
      float lcs = 0.0f;
#pragma unroll 8
      for (int t = 0; t < Ls; ++t) {
        int i = rbase + t0 + t;
        float s = (float)St[t0 + t][lane];
        lcs += s;
        float cs = cs_in + lcs;
        m = fmaxf(m, cs * (1.0f - s));
        if (i >= d) Ab[i * (TT + 1) - d] = (_Float16)(cs - m);
      }
    }
    cs_carry = tot;
    m_carry = mtot;
    __syncthreads();                       // St/Ssum/Gmax reuse next segment
  }
}

// ---------------------------------------------------------------------------
// K4: flash softmax(P)·V with SPLIT-K — 3072 one-wave phase-diverse blocks,
// split at jt=8. V is fp16-hi only, MFMA cluster in s_setprio(1), defer-
// rescale THR=1 (fp16-safe), depth-4 tree reductions (round-11 verified).
// ---------------------------------------------------------------------------
__global__ __launch_bounds__(64) void k_pv(
    const _Float16* __restrict__ A, const _Float16* __restrict__ vth,
    float* __restrict__ oatt, float* __restrict__ Opart, float* __restrict__ ml)
{
  const int lane = threadIdx.x;
  const int quad = lane >> 4, l16 = lane & 15;
  const int blk = blockIdx.x;              // 0..3071
  const int z = blk & 31;
  const int item = blk >> 5;               // 0..95
  int ti, band, jt0, jt1, chunk;
  bool split;
  if (item < 32) {                         // len-8 first chunks of split tiles
    ti = 8 + (item >> 2); band = item & 3; jt0 = 0; jt1 = 8; chunk = 0; split = true;
  } else {
    int i2 = item - 32;                    // 0..63
    int l = 8 - (i2 >> 3);                 // 8..1 (descending length)
    int sub = i2 & 7;
    band = sub & 3;
    if (sub < 4) { ti = l + 7; jt0 = 8; jt1 = ti + 1; chunk = 1; split = true; }
    else         { ti = l - 1; jt0 = 0; jt1 = ti + 1; chunk = 0; split = false; }
  }
  const _Float16* Az = A + (size_t)z * TT * TT;
  const _Float16* vh = vth + (size_t)z * DH * TT;

  const int i0 = ti * 64;
  const int irow = i0 + band * 16 + l16;   // this lane's P-row
  const float invi = 1.0f / (float)(irow + 1);
  f4 acc[4] = {};
  float m_old = -3e38f, l_run = 0.0f;

  float posu[16];
#pragma unroll
  for (int u = 0; u < 16; ++u)
    posu[u] = (float)((u >> 3) * 32 + quad * 8 + (u & 7)) * invi;
  const float jstep = 64.0f * invi;
  float jtoff = (float)jt0 * jstep;

  const _Float16* arow = &Az[(size_t)irow * TT];
  // A-row prefetch (one jt ahead).
  half8 nxt0 = *(const half8*)&arow[jt0 * 64 + quad * 8];
  half8 nxt1 = *(const half8*)&arow[jt0 * 64 + 32 + quad * 8];

  for (int jt = jt0; jt < jt1; ++jt) {
    const bool masked = (jt == ti);
    half8 cur0 = nxt0, cur1 = nxt1;
    if (jt + 1 < jt1) {
      nxt0 = *(const half8*)&arow[(jt + 1) * 64 + quad * 8];
      nxt1 = *(const half8*)&arow[(jt + 1) * 64 + 32 + quad * 8];
    }
    // Issue all V loads for this jt before the softmax VALU block.
    half8 fvh[2][4];
#pragma unroll
    for (int ks = 0; ks < 2; ++ks)
#pragma unroll
      for (int nt = 0; nt < 4; ++nt) {
        size_t vo = (size_t)(nt * 16 + l16) * TT + jt * 64 + ks * 32 + quad * 8;
        fvh[ks][nt] = *(const half8*)&vh[vo];
      }

    float sc[16];
#pragma unroll
    for (int u = 0; u < 8; ++u) { sc[u] = (float)cur0[u]; sc[8 + u] = (float)cur1[u]; }
#pragma unroll
    for (int u = 0; u < 16; ++u) {
      float v = sc[u] + (jtoff + posu[u]);
      int j = jt * 64 + (u >> 3) * 32 + quad * 8 + (u & 7);
      sc[u] = (masked && j > irow) ? -3e38f : v;
    }
    // Depth-4 max tree.
    float mt_;
    {
      float t8[8];
#pragma unroll
      for (int u = 0; u < 8; ++u) t8[u] = fmaxf(sc[u], sc[u + 8]);
      float t4[4];
#pragma unroll
      for (int u = 0; u < 4; ++u) t4[u] = fmaxf(t8[u], t8[u + 4]);
      float ta = fmaxf(t4[0], t4[2]), tb = fmaxf(t4[1], t4[3]);
      mt_ = fmaxf(ta, tb);
    }
    mt_ = fmaxf(mt_, __shfl_xor(mt_, 16, 64));
    mt_ = fmaxf(mt_, __shfl_xor(mt_, 32, 64));

    // THR = 1.0 score units: deferred P <= e^10 ~ 22026 < 65504 fp16 max.
    const bool defer = __all(mt_ <= m_old + 1.0f);
    float m_new = defer ? m_old : fmaxf(m_old, mt_);
#pragma unroll
    for (int u = 0; u < 16; ++u)
      sc[u] = __expf((sc[u] - m_new) * INV_TAU);
    // Depth-4 sum tree.
    float ls;
    {
      float s8[8];
#pragma unroll
      for (int u = 0; u < 8; ++u) s8[u] = sc[u] + sc[u + 8];
      float s4[4];
#pragma unroll
      for (int u = 0; u < 4; ++u) s4[u] = s8[u] + s8[u + 4];
      ls = (s4[0] + s4[2]) + (s4[1] + s4[3]);
    }
    ls += __shfl_xor(ls, 16, 64);
    ls += __shfl_xor(ls, 32, 64);
    if (!defer) {
      float alpha = __expf((m_old - m_new) * INV_TAU);
#pragma unroll
      for (int rr = 0; rr < 4; ++rr) {
        float ar = __shfl(alpha, quad * 4 + rr, 64);
#pragma unroll
        for (int nt = 0; nt < 4; ++nt) acc[nt][rr] *= ar;
      }
      l_run = l_run * alpha + ls;
      m_old = m_new;
    } else {
      l_run += ls;
    }
    __builtin_amdgcn_s_setprio(1);
#pragma unroll
    for (int ks = 0; ks < 2; ++ks) {
      half8 pa;
#pragma unroll
      for (int u = 0; u < 8; ++u) pa[u] = (_Float16)sc[ks * 8 + u];
#pragma unroll
      for (int nt = 0; nt < 4; ++nt)
        acc[nt] = __builtin_amdgcn_mfma_f32_16x16x32_f16(pa, fvh[ks][nt], acc[nt], 0, 0, 0);
    }
    __builtin_amdgcn_s_setprio(0);
    jtoff += jstep;
  }

  if (!split) {
#pragma unroll
    for (int rr = 0; rr < 4; ++rr) {
      float lr = __shfl(l_run, quad * 4 + rr, 64);
      float inv = 1.0f / lr;
      int orow = i0 + band * 16 + quad * 4 + rr;
#pragma unroll
      for (int nt = 0; nt < 4; ++nt)
        oatt[((size_t)z * TT + orow) * DH + nt * 16 + l16] = acc[nt][rr] * inv;
    }
  } else {
    // unnormalized partial + per-row (m, l)
    if (quad == 0) {
      int prow = i0 + band * 16 + l16 - 512;
      size_t mo = (((size_t)chunk * 32 + z) * 512 + prow) * 2;
      ml[mo + 0] = m_old;
      ml[mo + 1] = l_run;
    }
#pragma unroll
    for (int rr = 0; rr < 4; ++rr) {
      int prow = i0 + band * 16 + quad * 4 + rr - 512;
      size_t po = (((size_t)chunk * 32 + z) * 512 + prow) * 64;
#pragma unroll
      for (int nt = 0; nt < 4; ++nt)
        Opart[po + nt * 16 + l16] = acc[nt][rr];
    }
  }
}

// ---------------------------------------------------------------------------
// K6: per-head output projection + fused split-K combine for rows >= 512.
// Inner product split into two 32-deep halves (8 independent FMA chains).
// ---------------------------------------------------------------------------
__global__ __launch_bounds__(256) void k_oproj(
    const float* __restrict__ oatt, const float* __restrict__ wo,
    const float* __restrict__ Opart, const float* __restrict__ ml,
    float* __restrict__ out)
{
  __shared__ float Wl[64][64];
  __shared__ float Ol[16][64];
  const int z = blockIdx.y;                // b*NH + h
  const int t0 = blockIdx.x * 16;
  const int b = z >> 3, h = z & 7;
  const int tid = threadIdx.x;
  const float* wb = wo + (size_t)h * 64 * 64;
#pragma unroll
  for (int u = 0; u < 4; ++u) {
    int q = tid + 256 * u;
    int dd = q >> 4, e4 = (q & 15) * 4;
    *(float4*)&Wl[dd][e4] = *(const float4*)&wb[(size_t)dd * 64 + e4];
  }
  {
    int rr = tid >> 4, d4 = (tid & 15) * 4;
    int trow = t0 + rr;
    if (trow < 512) {
      *(float4*)&Ol[rr][d4] = *(const float4*)&oatt[((size_t)z * TT + trow) * DH + d4];
    } else {
      int pr = trow - 512;
      size_t m0o = (((size_t)0 * 32 + z) * 512 + pr) * 2;
      size_t m1o = (((size_t)1 * 32 + z) * 512 + pr) * 2;
      float m0 = ml[m0o], l0 = ml[m0o + 1];
      float m1 = ml[m1o], l1 = ml[m1o + 1];
      float mm = fmaxf(m0, m1);
      float w0 = __expf((m0 - mm) * INV_TAU);
      float w1 = __expf((m1 - mm) * INV_TAU);
      float inv = 1.0f / (l0 * w0 + l1 * w1);
      float4 o0 = *(const float4*)&Opart[(((size_t)0 * 32 + z) * 512 + pr) * 64 + d4];
      float4 o1 = *(const float4*)&Opart[(((size_t)1 * 32 + z) * 512 + pr) * 64 + d4];
      Ol[rr][d4 + 0] = (o0.x * w0 + o1.x * w1) * inv;
      Ol[rr][d4 + 1] = (o0.y * w0 + o1.y * w1) * inv;
      Ol[rr][d4 + 2] = (o0.z * w0 + o1.z * w1) * inv;
      Ol[rr][d4 + 3] = (o0.w * w0 + o1.w * w1) * inv;
    }
  }
  __syncthreads();
  const int rg = tid >> 6, e = tid & 63;
  float a0 = 0, a1 = 0, a2 = 0, a3 = 0;
  float b0 = 0, b1 = 0, b2 = 0, b3 = 0;
#pragma unroll
  for (int dd = 0; dd < 32; ++dd) {
    float wv0 = Wl[dd][e];
    float wv1 = Wl[dd + 32][e];
    a0 += Ol[rg * 4 + 0][dd] * wv0;  b0 += Ol[rg * 4 + 0][dd + 32] * wv1;
    a1 += Ol[rg * 4 + 1][dd] * wv0;  b1 += Ol[rg * 4 + 1][dd + 32] * wv1;
    a2 += Ol[rg * 4 + 2][dd] * wv0;  b2 += Ol[rg * 4 + 2][dd + 32] * wv1;
    a3 += Ol[rg * 4 + 3][dd] * wv0;  b3 += Ol[rg * 4 + 3][dd + 32] * wv1;
  }
  size_t ob = ((size_t)b * TT + t0 + rg * 4) * DD + h * 64 + e;
  out[ob] = a0 + b0; out[ob + DD] = a1 + b1;
  out[ob + 2 * DD] = a2 + b2; out[ob + 3 * DD] = a3 + b3;
}

// ---------------------------------------------------------------------------
// ws layout (<=164 MB):
//  [0,2) qh fp16 ([2,4) free)  [8,10) kh fp16  [12,14) kl fp16
//  (oatt aliases [0,8) after k_qkv)
//  [16,18) vsh fp16  [24,28) vth fp16 (hi only)
//  [33,97) A fp16    ([33,41) doubles as xh/xl before k_qkv overwrites it)
//  [97,113) Opart    [113,113.25) ml
//  [161,162.5) wth   [162.5,164) wtl
// ---------------------------------------------------------------------------
extern "C" void kernel_launch(void* const* d_in, const int* in_sizes, int n_in,
                              void* d_out, int out_size, void* d_ws, size_t ws_size,
                              hipStream_t stream)
{
  (void)in_sizes; (void)n_in; (void)out_size; (void)ws_size;
  const float* x  = (const float*)d_in[0];
  const float* wq = (const float*)d_in[1];
  const float* wk = (const float*)d_in[2];
  const float* wv = (const float*)d_in[3];
  const float* wo = (const float*)d_in[4];
  float* out = (float*)d_out;

  char* ws = (char*)d_ws;
  const size_t MB = 1024 * 1024;
  _Float16*       qh = (_Float16*)(ws);
  _Float16*       kh = (_Float16*)(ws + 8 * MB);
  _Float16*       kl = (_Float16*)(ws + 12 * MB);
  _Float16*       vsh = (_Float16*)(ws + 16 * MB);
  _Float16*       vth = (_Float16*)(ws + 24 * MB);
  float*          oatt = (float*)(ws);                    // aliases qh (dead)
  _Float16*       A  = (_Float16*)(ws + 33 * MB);
  unsigned short* xh = (unsigned short*)(ws + 33 * MB);   // aliases A (dead by k_qkv)
  unsigned short* xl = (unsigned short*)(ws + 37 * MB);
  float*          Opart = (float*)(ws + 97 * MB);
  float*          ml = (float*)(ws + 113 * MB);
  unsigned short* wth = (unsigned short*)(ws + 161 * MB);
  unsigned short* wtl = (unsigned short*)(ws + 161 * MB + 1536 * 1024);

  hipLaunchKernelGGL(k_prep, dim3(2048 + 192), dim3(256), 0, stream,
                     x, wq, wk, wv, xh, xl, wth, wtl);
  hipLaunchKernelGGL(k_proj_mfma, dim3(12, 64), dim3(256), 0, stream,
                     xh, xl, wth, wtl, qh, kh, kl, vsh);
  hipLaunchKernelGGL(k_qkv, dim3(1088 + 512), dim3(256), 0, stream,
                     qh, kh, kl, A, vsh, vth);
  hipLaunchKernelGGL(k_scan, dim3(512), dim3(1024), 0, stream, A);
  hipLaunchKernelGGL(k_pv, dim3(3072), dim3(64), 0, stream, A, vth,
                     oatt, Opart, ml);
  hipLaunchKernelGGL(k_oproj, dim3(64, 32), dim3(256), 0, stream,
                     oatt, wo, Opart, ml, out);
}

// Round 13
// 173.317 us; speedup vs baseline: 1.0070x; 1.0070x over previous
//
#include <hip/hip_runtime.h>
#include <math.h>

#define BB    4
#define TT    1024
#define DD    512
#define NH    8
#define DH    64
#define BH    32          // BB*NH
#define INV_TAU 10.0f

typedef __attribute__((ext_vector_type(8))) short short8;
typedef __attribute__((ext_vector_type(4))) float f4;
typedef __attribute__((ext_vector_type(8))) _Float16 half8;
typedef __attribute__((ext_vector_type(2))) _Float16 half2v;

typedef __attribute__((address_space(3))) unsigned int lds_u32;
typedef __attribute__((address_space(1))) const unsigned short glob_u16;

__device__ inline unsigned short f2bf(float f) {
  unsigned u = __float_as_uint(f);
  u += 0x7FFFu + ((u >> 16) & 1u);        // round-to-nearest-even
  return (unsigned short)(u >> 16);
}
__device__ inline float bf2f(unsigned short h) {
  return __uint_as_float(((unsigned)h) << 16);
}

// ---------------------------------------------------------------------------
// K0 "prep": merged split_x (blocks 0..2047) + split_wt (blocks 2048..2239).
// ---------------------------------------------------------------------------
__global__ __launch_bounds__(256) void k_prep(
    const float* __restrict__ x, const float* __restrict__ wq,
    const float* __restrict__ wk, const float* __restrict__ wv,
    unsigned short* __restrict__ xh, unsigned short* __restrict__ xl,
    unsigned short* __restrict__ wth, unsigned short* __restrict__ wtl)
{
  __shared__ float Wf[64][65];
  const int blk = blockIdx.x;
  const int tid = threadIdx.x;
  if (blk < 2048) {
    const int i = (blk * 256 + tid) * 4;
    float4 v = *(const float4*)&x[i];
    ushort4 h, l;
    h.x = f2bf(v.x); l.x = f2bf(v.x - bf2f(h.x));
    h.y = f2bf(v.y); l.y = f2bf(v.y - bf2f(h.y));
    h.z = f2bf(v.z); l.z = f2bf(v.z - bf2f(h.z));
    h.w = f2bf(v.w); l.w = f2bf(v.w - bf2f(h.w));
    *(ushort4*)&xh[i] = h;
    *(ushort4*)&xl[i] = l;
    return;
  }
  const int b = blk - 2048;                // 0..191
  const int ten = b >> 6;                  // 0..2
  const int r = b & 63;
  const int n0 = (r & 7) * 64, k0 = (r >> 3) * 64;
  const float* W = (ten == 0) ? wq : ((ten == 1) ? wk : wv);
#pragma unroll
  for (int p = 0; p < 4; ++p) {
    int kk = p * 16 + (tid >> 4);
    int nn = (tid & 15) * 4;
    float4 v = *(const float4*)&W[(size_t)(k0 + kk) * 512 + n0 + nn];
    Wf[kk][nn + 0] = v.x; Wf[kk][nn + 1] = v.y;
    Wf[kk][nn + 2] = v.z; Wf[kk][nn + 3] = v.w;
  }
  __syncthreads();
  const int n = tid >> 2, kq = tid & 3;
  size_t base = ((size_t)(ten * 512 + n0 + n)) * 512 + k0 + kq * 16;
#pragma unroll
  for (int jj = 0; jj < 4; ++jj) {
    ushort4 h, l;
    float f0 = Wf[kq * 16 + jj * 4 + 0][n];
    float f1 = Wf[kq * 16 + jj * 4 + 1][n];
    float f2 = Wf[kq * 16 + jj * 4 + 2][n];
    float f3 = Wf[kq * 16 + jj * 4 + 3][n];
    h.x = f2bf(f0); l.x = f2bf(f0 - bf2f(h.x));
    h.y = f2bf(f1); l.y = f2bf(f1 - bf2f(h.y));
    h.z = f2bf(f2); l.z = f2bf(f2 - bf2f(h.z));
    h.w = f2bf(f3); l.w = f2bf(f3 - bf2f(h.w));
    *(ushort4*)&wth[base + jj * 4] = h;
    *(ushort4*)&wtl[base + jj * 4] = l;
  }
}

// ---------------------------------------------------------------------------
// K1: QKV projection via bf16x3 MFMA + fused per-head softmax.
// Staging via global_load_lds width=16 into linear LDS [R][32] with the
// both-sides XOR chunk swizzle (round-10, verified bit-identical).
// Epilogue: Q fp16, K fp16 hi+lo. V: TRANSPOSED IN-KERNEL — staging LDS is
// dead after the K-loop, so it is reclaimed as Vt[128][72] fp16 ([head*64+d]
// [t], 72-pad = 16B-aligned rows); after a barrier each thread streams
// coalesced 16B rows straight to vth. Removes the whole vsplit pass
// (512 k_qkv blocks + 8MB traffic); values bitwise identical.
// ---------------------------------------------------------------------------
__global__ __launch_bounds__(256) void k_proj_mfma(
    const unsigned short* __restrict__ xh, const unsigned short* __restrict__ xl,
    const unsigned short* __restrict__ wth, const unsigned short* __restrict__ wtl,
    _Float16* __restrict__ qh, _Float16* __restrict__ kh,
    _Float16* __restrict__ kl, _Float16* __restrict__ vth)
{
  __shared__ __align__(16) char pool[24576];
  unsigned short (*Ah)[32] = (unsigned short (*)[32])(pool);          // 4KB
  unsigned short (*Al)[32] = (unsigned short (*)[32])(pool + 4096);   // 4KB
  unsigned short (*Bh)[32] = (unsigned short (*)[32])(pool + 8192);   // 8KB
  unsigned short (*Bl)[32] = (unsigned short (*)[32])(pool + 16384);  // 8KB
  _Float16 (*Vt)[72] = (_Float16 (*)[72])(pool);  // 18.4KB, reclaims staging

  const int tid = threadIdx.x;
  const int n0g = blockIdx.x * 128;        // 0..1408
  const int m0 = blockIdx.y * 64;          // 0..4032
  const int w = tid >> 6, lane = tid & 63;
  const int mw = (w & 1) * 32, nw = (w >> 1) * 64;
  const int quad = lane >> 4, l16 = lane & 15;

  const int rl = lane >> 2;
  const int swz = ((lane & 3) ^ (rl & 3)) * 8;  // fetched chunk, elements

  f4 acc[2][4] = {};

  for (int k0 = 0; k0 < DD; k0 += 32) {
    {
      size_t src = (size_t)(m0 + w * 16 + rl) * DD + k0 + swz;
      __builtin_amdgcn_global_load_lds((glob_u16*)&xh[src],
                                       (lds_u32*)&Ah[w * 16][0], 16, 0, 0);
      __builtin_amdgcn_global_load_lds((glob_u16*)&xl[src],
                                       (lds_u32*)&Al[w * 16][0], 16, 0, 0);
    }
    {
      size_t s0 = (size_t)(n0g + w * 32 + rl) * DD + k0 + swz;
      size_t s1 = (size_t)(n0g + w * 32 + 16 + rl) * DD + k0 + swz;
      __builtin_amdgcn_global_load_lds((glob_u16*)&wth[s0],
                                       (lds_u32*)&Bh[w * 32][0], 16, 0, 0);
      __builtin_amdgcn_global_load_lds((glob_u16*)&wth[s1],
                                       (lds_u32*)&Bh[w * 32 + 16][0], 16, 0, 0);
      __builtin_amdgcn_global_load_lds((glob_u16*)&wtl[s0],
                                       (lds_u32*)&Bl[w * 32][0], 16, 0, 0);
      __builtin_amdgcn_global_load_lds((glob_u16*)&wtl[s1],
                                       (lds_u32*)&Bl[w * 32 + 16][0], 16, 0, 0);
    }
    __syncthreads();                       // drains vmcnt before barrier

    short8 fbh[4], fbl[4];
#pragma unroll
    for (int nt = 0; nt < 4; ++nt) {
      int rb = nw + nt * 16 + l16;
      int cb = ((quad ^ (rb & 3)) * 8);
      fbh[nt] = *(const short8*)&Bh[rb][cb];
      fbl[nt] = *(const short8*)&Bl[rb][cb];
    }
#pragma unroll
    for (int mt = 0; mt < 2; ++mt) {
      int ra = mw + mt * 16 + l16;
      int ca = ((quad ^ (ra & 3)) * 8);
      short8 fah = *(const short8*)&Ah[ra][ca];
      short8 fal = *(const short8*)&Al[ra][ca];
#pragma unroll
      for (int nt = 0; nt < 4; ++nt) {
        acc[mt][nt] = __builtin_amdgcn_mfma_f32_16x16x32_bf16(fah, fbh[nt], acc[mt][nt], 0, 0, 0);
        acc[mt][nt] = __builtin_amdgcn_mfma_f32_16x16x32_bf16(fah, fbl[nt], acc[mt][nt], 0, 0, 0);
        acc[mt][nt] = __builtin_amdgcn_mfma_f32_16x16x32_bf16(fal, fbh[nt], acc[mt][nt], 0, 0, 0);
      }
    }
    __syncthreads();                       // staging dead after this (last iter)
  }

  const int tensor = n0g >> 9;
  const int ncol = (n0g & 511) + nw;
  const int h = ncol >> 6;
#pragma unroll
  for (int mt = 0; mt < 2; ++mt) {
#pragma unroll
    for (int r = 0; r < 4; ++r) {
      float v0 = acc[mt][0][r], v1 = acc[mt][1][r];
      float v2 = acc[mt][2][r], v3 = acc[mt][3][r];
      float mx = fmaxf(fmaxf(v0, v1), fmaxf(v2, v3));
#pragma unroll
      for (int msk = 1; msk <= 8; msk <<= 1) mx = fmaxf(mx, __shfl_xor(mx, msk, 64));
      float e0 = __expf((v0 - mx) * INV_TAU);
      float e1 = __expf((v1 - mx) * INV_TAU);
      float e2 = __expf((v2 - mx) * INV_TAU);
      float e3 = __expf((v3 - mx) * INV_TAU);
      float sm = (e0 + e1) + (e2 + e3);
#pragma unroll
      for (int msk = 1; msk <= 8; msk <<= 1) sm += __shfl_xor(sm, msk, 64);
      float inv = 1.0f / sm;
      int row = m0 + mw + mt * 16 + quad * 4 + r;
      float e[4] = {e0 * inv, e1 * inv, e2 * inv, e3 * inv};
      if (tensor == 2) {
        int tl = mw + mt * 16 + quad * 4 + r;   // row - m0
#pragma unroll
        for (int c = 0; c < 4; ++c)
          Vt[nw + c * 16 + l16][tl] = (_Float16)e[c];
      } else {
        int b = row >> 10, t = row & 1023;
        size_t base = (((size_t)b * NH + h) * TT + t) * DH;
        if (tensor == 0) {
#pragma unroll
          for (int c = 0; c < 4; ++c) qh[base + l16 + c * 16] = (_Float16)e[c];
        } else {
#pragma unroll
          for (int c = 0; c < 4; ++c) {
            _Float16 hh = (_Float16)e[c];
            kh[base + l16 + c * 16] = hh;
            kl[base + l16 + c * 16] = (_Float16)(e[c] - (float)hh);
          }
        }
      }
    }
  }
  if (tensor == 2) {
    __syncthreads();                       // all Vt writes visible
    const int hrow = tid >> 1;             // 0..127 (head*64 + d)
    const int tseg = (tid & 1) * 32;
    const int hg = ((n0g & 511) >> 6) + (hrow >> 6);
    const int dd = hrow & 63;
    const int bb = m0 >> 10, t0g = m0 & 1023;
    size_t ob = (((size_t)bb * NH + hg) * DH + dd) * TT + t0g + tseg;
#pragma unroll
    for (int k = 0; k < 4; ++k)
      *(half8*)&vth[ob + k * 8] = *(const half8*)&Vt[hrow][tseg + k * 8];
  }
}

// ---------------------------------------------------------------------------
// K2 "qkv": QK^T only (vsplit moved into k_proj). Grid 1088.
// QK^T in fp16, 2 terms: A = qh*(kh+kl) (round-9 verified).
// ---------------------------------------------------------------------------
__global__ __launch_bounds__(256) void k_qkv(
    const _Float16* __restrict__ qh, const _Float16* __restrict__ kh,
    const _Float16* __restrict__ kl, _Float16* __restrict__ A)
{
  const int tid = threadIdx.x;
  const int gid = blockIdx.x * 4 + (tid >> 6);
  const int z = gid / 136;
  const int lx = gid - z * 136;
  int ti = (int)((sqrtf(8.0f * lx + 1.0f) - 1.0f) * 0.5f);
  while ((ti + 1) * (ti + 2) / 2 <= lx) ++ti;
  while (ti * (ti + 1) / 2 > lx) --ti;
  const int tj = lx - ti * (ti + 1) / 2;
  const int i0 = ti * 64, j0 = tj * 64;
  const int lane = tid & 63;
  const int quad = lane >> 4, l16 = lane & 15;
  const size_t zb = (size_t)z * TT * DH;

  half8 fbh[4][2], fbl[4][2];
#pragma unroll
  for (int nt = 0; nt < 4; ++nt)
#pragma unroll
    for (int ks = 0; ks < 2; ++ks) {
      size_t o = zb + (size_t)(j0 + nt * 16 + l16) * DH + ks * 32 + quad * 8;
      fbh[nt][ks] = *(const half8*)&kh[o];
      fbl[nt][ks] = *(const half8*)&kl[o];
    }

  f4 acc[4][4] = {};
#pragma unroll
  for (int mt = 0; mt < 4; ++mt) {
    half8 fah[2];
#pragma unroll
    for (int ks = 0; ks < 2; ++ks) {
      size_t o = zb + (size_t)(i0 + mt * 16 + l16) * DH + ks * 32 + quad * 8;
      fah[ks] = *(const half8*)&qh[o];
    }
#pragma unroll
    for (int nt = 0; nt < 4; ++nt)
#pragma unroll
      for (int ks = 0; ks < 2; ++ks) {
        acc[mt][nt] = __builtin_amdgcn_mfma_f32_16x16x32_f16(fah[ks], fbh[nt][ks], acc[mt][nt], 0, 0, 0);
        acc[mt][nt] = __builtin_amdgcn_mfma_f32_16x16x32_f16(fah[ks], fbl[nt][ks], acc[mt][nt], 0, 0, 0);
      }
  }

  _Float16* Ab = A + (size_t)z * TT * TT;
#pragma unroll
  for (int mt = 0; mt < 4; ++mt)
#pragma unroll
    for (int nt = 0; nt < 4; ++nt)
#pragma unroll
      for (int r = 0; r < 4; ++r)
        Ab[(size_t)(i0 + mt * 16 + quad * 4 + r) * TT + j0 + nt * 16 + l16] =
            (_Float16)acc[mt][nt][r];
}

// ---------------------------------------------------------------------------
// K3: diagonal run-length scan — single global read + single global write.
// Phase A fuses staging with HALF-sums; phase B runs two independent
// prefix/max chains (round-12). St[512][64] fp16 = 64KB.
// ---------------------------------------------------------------------------
__global__ __launch_bounds__(1024) void k_scan(_Float16* __restrict__ A)
{
  __shared__ _Float16 St[512][64];         // 64 KB band staging
  __shared__ float Ssum[16][64];
  __shared__ float Gmax[16][64];
  const int blk = blockIdx.x;              // 0..511
  const int p = blk >> 5;                  // 0..15
  const int xb = (p < 8) ? p : (23 - p);   // complementary pairing across CUs
  const int z = blk & 31;
  const int lane = threadIdx.x & 63;
  const int w = threadIdx.x >> 6;          // wave 0..15
  _Float16* __restrict__ Ab = A + (size_t)z * TT * TT;
  const int dbase = xb * 64;
  const int d = dbase + lane;              // this lane's diagonal
  const int R = TT - dbase;                // rows in this diagonal band
  const int nseg = (R > 512) ? 2 : 1;
  const int Rseg = R / nseg;               // <= 512 rows per segment
  const int Ls = Rseg >> 4;                // rows per wave-chunk (even)

  float cs_carry = 0.0f, m_carry = 0.0f;
  for (int sg = 0; sg < nseg; ++sg) {
    const int rbase = dbase + sg * Rseg;
    const int t0 = w * Ls;
    const int H = Ls >> 1;

    // Phase A: stage + fused HALF sums (two independent chains).
    float S0 = 0.0f, S1 = 0.0f;
    for (int t = 0; t < H; ++t) {
      int ia = rbase + t0 + t;
      int ib = ia + H;
      float sa = (float)Ab[ia * (TT + 1) - d];
      float sb = (float)Ab[ib * (TT + 1) - d];
      float a0 = (ia >= d) ? sa : 0.0f;
      float a1 = (ib >= d) ? sb : 0.0f;
      St[t0 + t][lane] = (_Float16)a0;
      St[t0 + H + t][lane] = (_Float16)a1;
      S0 += a0;
      S1 += a1;
    }
    Ssum[w][lane] = S0 + S1;
    __syncthreads();

    float cs_in = cs_carry;
    float tot = cs_carry;
    for (int ww = 0; ww < 16; ++ww) {
      float sv = Ssum[ww][lane];
      cs_in += (ww < w) ? sv : 0.0f;
      tot += sv;
    }

    // Phase B: two independent prefix/max chains over the chunk halves.
    {
      float lcs0 = 0.0f, lcs1 = S0, gm0 = 0.0f, gm1 = 0.0f;
#pragma unroll 4
      for (int t = 0; t < H; ++t) {
        float s0 = (float)St[t0 + t][lane];
        float s1 = (float)St[t0 + H + t][lane];
        lcs0 += s0;
        lcs1 += s1;
        gm0 = fmaxf(gm0, (cs_in + lcs0) * (1.0f - s0));
        gm1 = fmaxf(gm1, (cs_in + lcs1) * (1.0f - s1));
      }
      Gmax[w][lane] = fmaxf(gm0, gm1);
    }
    __syncthreads();

    float m = m_carry;
    float mtot = m_carry;
    for (int ww = 0; ww < 16; ++ww) {
      float gv = Gmax[ww][lane];
      m = fmaxf(m, (ww < w) ? gv : 0.0f);  // values are >= 0
      mtot = fmaxf(mtot, gv);
    }

    // Phase C: finalize, single coalesced global write (serial by nature).
    {
      float lcs = 0.0f;
#pragma unroll 8
      for (int t = 0; t < Ls; ++t) {
        int i = rbase + t0 + t;
        float s = (float)St[t0 + t][lane];
        lcs += s;
        float cs = cs_in + lcs;
        m = fmaxf(m, cs * (1.0f - s));
        if (i >= d) Ab[i * (TT + 1) - d] = (_Float16)(cs - m);
      }
    }
    cs_carry = tot;
    m_carry = mtot;
    __syncthreads();                       // St/Ssum/Gmax reuse next segment
  }
}

// ---------------------------------------------------------------------------
// K4: flash softmax(P)·V with SPLIT-K — 3072 one-wave phase-diverse blocks,
// split at jt=8. V is fp16-hi only, MFMA cluster in s_setprio(1), defer-
// rescale THR=1 (fp16-safe), depth-4 tree reductions (round-11). NEW:
// masked-tile bias+mask hoisted to a block-uniform branch (jt==ti is
// uniform) — saves ~32 VALU/jt on all non-diagonal iterations.
// ---------------------------------------------------------------------------
__global__ __launch_bounds__(64) void k_pv(
    const _Float16* __restrict__ A, const _Float16* __restrict__ vth,
    float* __restrict__ oatt, float* __restrict__ Opart, float* __restrict__ ml)
{
  const int lane = threadIdx.x;
  const int quad = lane >> 4, l16 = lane & 15;
  const int blk = blockIdx.x;              // 0..3071
  const int z = blk & 31;
  const int item = blk >> 5;               // 0..95
  int ti, band, jt0, jt1, chunk;
  bool split;
  if (item < 32) {                         // len-8 first chunks of split tiles
    ti = 8 + (item >> 2); band = item & 3; jt0 = 0; jt1 = 8; chunk = 0; split = true;
  } else {
    int i2 = item - 32;                    // 0..63
    int l = 8 - (i2 >> 3);                 // 8..1 (descending length)
    int sub = i2 & 7;
    band = sub & 3;
    if (sub < 4) { ti = l + 7; jt0 = 8; jt1 = ti + 1; chunk = 1; split = true; }
    else         { ti = l - 1; jt0 = 0; jt1 = ti + 1; chunk = 0; split = false; }
  }
  const _Float16* Az = A + (size_t)z * TT * TT;
  const _Float16* vh = vth + (size_t)z * DH * TT;

  const int i0 = ti * 64;
  const int irow = i0 + band * 16 + l16;   // this lane's P-row
  const float invi = 1.0f / (float)(irow + 1);
  f4 acc[4] = {};
  float m_old = -3e38f, l_run = 0.0f;

  float posu[16];
#pragma unroll
  for (int u = 0; u < 16; ++u)
    posu[u] = (float)((u >> 3) * 32 + quad * 8 + (u & 7)) * invi;
  const float jstep = 64.0f * invi;
  float jtoff = (float)jt0 * jstep;

  const _Float16* arow = &Az[(size_t)irow * TT];
  // A-row prefetch (one jt ahead).
  half8 nxt0 = *(const half8*)&arow[jt0 * 64 + quad * 8];
  half8 nxt1 = *(const half8*)&arow[jt0 * 64 + 32 + quad * 8];

  for (int jt = jt0; jt < jt1; ++jt) {
    const bool masked = (jt == ti);        // block-uniform
    half8 cur0 = nxt0, cur1 = nxt1;
    if (jt + 1 < jt1) {
      nxt0 = *(const half8*)&arow[(jt + 1) * 64 + quad * 8];
      nxt1 = *(const half8*)&arow[(jt + 1) * 64 + 32 + quad * 8];
    }
    // Issue all V loads for this jt before the softmax VALU block.
    half8 fvh[2][4];
#pragma unroll
    for (int ks = 0; ks < 2; ++ks)
#pragma unroll
      for (int nt = 0; nt < 4; ++nt) {
        size_t vo = (size_t)(nt * 16 + l16) * TT + jt * 64 + ks * 32 + quad * 8;
        fvh[ks][nt] = *(const half8*)&vh[vo];
      }

    float sc[16];
#pragma unroll
    for (int u = 0; u < 8; ++u) { sc[u] = (float)cur0[u]; sc[8 + u] = (float)cur1[u]; }
    if (masked) {
#pragma unroll
      for (int u = 0; u < 16; ++u) {
        float v = sc[u] + (jtoff + posu[u]);
        int j = jt * 64 + (u >> 3) * 32 + quad * 8 + (u & 7);
        sc[u] = (j > irow) ? -3e38f : v;
      }
    } else {
#pragma unroll
      for (int u = 0; u < 16; ++u) sc[u] += jtoff + posu[u];
    }
    // Depth-4 max tree.
    float mt_;
    {
      float t8[8];
#pragma unroll
      for (int u = 0; u < 8; ++u) t8[u] = fmaxf(sc[u], sc[u + 8]);
      float t4[4];
#pragma unroll
      for (int u = 0; u < 4; ++u) t4[u] = fmaxf(t8[u], t8[u + 4]);
      float ta = fmaxf(t4[0], t4[2]), tb = fmaxf(t4[1], t4[3]);
      mt_ = fmaxf(ta, tb);
    }
    mt_ = fmaxf(mt_, __shfl_xor(mt_, 16, 64));
    mt_ = fmaxf(mt_, __shfl_xor(mt_, 32, 64));

    // THR = 1.0 score units: deferred P <= e^10 ~ 22026 < 65504 fp16 max.
    const bool defer = __all(mt_ <= m_old + 1.0f);
    float m_new = defer ? m_old : fmaxf(m_old, mt_);
#pragma unroll
    for (int u = 0; u < 16; ++u)
      sc[u] = __expf((sc[u] - m_new) * INV_TAU);
    // Depth-4 sum tree.
    float ls;
    {
      float s8[8];
#pragma unroll
      for (int u = 0; u < 8; ++u) s8[u] = sc[u] + sc[u + 8];
      float s4[4];
#pragma unroll
      for (int u = 0; u < 4; ++u) s4[u] = s8[u] + s8[u + 4];
      ls = (s4[0] + s4[2]) + (s4[1] + s4[3]);
    }
    ls += __shfl_xor(ls, 16, 64);
    ls += __shfl_xor(ls, 32, 64);
    if (!defer) {
      float alpha = __expf((m_old - m_new) * INV_TAU);
#pragma unroll
      for (int rr = 0; rr < 4; ++rr) {
        float ar = __shfl(alpha, quad * 4 + rr, 64);
#pragma unroll
        for (int nt = 0; nt < 4; ++nt) acc[nt][rr] *= ar;
      }
      l_run = l_run * alpha + ls;
      m_old = m_new;
    } else {
      l_run += ls;
    }
    __builtin_amdgcn_s_setprio(1);
#pragma unroll
    for (int ks = 0; ks < 2; ++ks) {
      half8 pa;
#pragma unroll
      for (int u = 0; u < 8; ++u) pa[u] = (_Float16)sc[ks * 8 + u];
#pragma unroll
      for (int nt = 0; nt < 4; ++nt)
        acc[nt] = __builtin_amdgcn_mfma_f32_16x16x32_f16(pa, fvh[ks][nt], acc[nt], 0, 0, 0);
    }
    __builtin_amdgcn_s_setprio(0);
    jtoff += jstep;
  }

  if (!split) {
#pragma unroll
    for (int rr = 0; rr < 4; ++rr) {
      float lr = __shfl(l_run, quad * 4 + rr, 64);
      float inv = 1.0f / lr;
      int orow = i0 + band * 16 + quad * 4 + rr;
#pragma unroll
      for (int nt = 0; nt < 4; ++nt)
        oatt[((size_t)z * TT + orow) * DH + nt * 16 + l16] = acc[nt][rr] * inv;
    }
  } else {
    // unnormalized partial + per-row (m, l)
    if (quad == 0) {
      int prow = i0 + band * 16 + l16 - 512;
      size_t mo = (((size_t)chunk * 32 + z) * 512 + prow) * 2;
      ml[mo + 0] = m_old;
      ml[mo + 1] = l_run;
    }
#pragma unroll
    for (int rr = 0; rr < 4; ++rr) {
      int prow = i0 + band * 16 + quad * 4 + rr - 512;
      size_t po = (((size_t)chunk * 32 + z) * 512 + prow) * 64;
#pragma unroll
      for (int nt = 0; nt < 4; ++nt)
        Opart[po + nt * 16 + l16] = acc[nt][rr];
    }
  }
}

// ---------------------------------------------------------------------------
// K6: per-head output projection + fused split-K combine for rows >= 512.
// Inner product split into two 32-deep halves (8 independent FMA chains).
// ---------------------------------------------------------------------------
__global__ __launch_bounds__(256) void k_oproj(
    const float* __restrict__ oatt, const float* __restrict__ wo,
    const float* __restrict__ Opart, const float* __restrict__ ml,
    float* __restrict__ out)
{
  __shared__ float Wl[64][64];
  __shared__ float Ol[16][64];
  const int z = blockIdx.y;                // b*NH + h
  const int t0 = blockIdx.x * 16;
  const int b = z >> 3, h = z & 7;
  const int tid = threadIdx.x;
  const float* wb = wo + (size_t)h * 64 * 64;
#pragma unroll
  for (int u = 0; u < 4; ++u) {
    int q = tid + 256 * u;
    int dd = q >> 4, e4 = (q & 15) * 4;
    *(float4*)&Wl[dd][e4] = *(const float4*)&wb[(size_t)dd * 64 + e4];
  }
  {
    int rr = tid >> 4, d4 = (tid & 15) * 4;
    int trow = t0 + rr;
    if (trow < 512) {
      *(float4*)&Ol[rr][d4] = *(const float4*)&oatt[((size_t)z * TT + trow) * DH + d4];
    } else {
      int pr = trow - 512;
      size_t m0o = (((size_t)0 * 32 + z) * 512 + pr) * 2;
      size_t m1o = (((size_t)1 * 32 + z) * 512 + pr) * 2;
      float m0 = ml[m0o], l0 = ml[m0o + 1];
      float m1 = ml[m1o], l1 = ml[m1o + 1];
      float mm = fmaxf(m0, m1);
      float w0 = __expf((m0 - mm) * INV_TAU);
      float w1 = __expf((m1 - mm) * INV_TAU);
      float inv = 1.0f / (l0 * w0 + l1 * w1);
      float4 o0 = *(const float4*)&Opart[(((size_t)0 * 32 + z) * 512 + pr) * 64 + d4];
      float4 o1 = *(const float4*)&Opart[(((size_t)1 * 32 + z) * 512 + pr) * 64 + d4];
      Ol[rr][d4 + 0] = (o0.x * w0 + o1.x * w1) * inv;
      Ol[rr][d4 + 1] = (o0.y * w0 + o1.y * w1) * inv;
      Ol[rr][d4 + 2] = (o0.z * w0 + o1.z * w1) * inv;
      Ol[rr][d4 + 3] = (o0.w * w0 + o1.w * w1) * inv;
    }
  }
  __syncthreads();
  const int rg = tid >> 6, e = tid & 63;
  float a0 = 0, a1 = 0, a2 = 0, a3 = 0;
  float b0 = 0, b1 = 0, b2 = 0, b3 = 0;
#pragma unroll
  for (int dd = 0; dd < 32; ++dd) {
    float wv0 = Wl[dd][e];
    float wv1 = Wl[dd + 32][e];
    a0 += Ol[rg * 4 + 0][dd] * wv0;  b0 += Ol[rg * 4 + 0][dd + 32] * wv1;
    a1 += Ol[rg * 4 + 1][dd] * wv0;  b1 += Ol[rg * 4 + 1][dd + 32] * wv1;
    a2 += Ol[rg * 4 + 2][dd] * wv0;  b2 += Ol[rg * 4 + 2][dd + 32] * wv1;
    a3 += Ol[rg * 4 + 3][dd] * wv0;  b3 += Ol[rg * 4 + 3][dd + 32] * wv1;
  }
  size_t ob = ((size_t)b * TT + t0 + rg * 4) * DD + h * 64 + e;
  out[ob] = a0 + b0; out[ob + DD] = a1 + b1;
  out[ob + 2 * DD] = a2 + b2; out[ob + 3 * DD] = a3 + b3;
}

// ---------------------------------------------------------------------------
// ws layout (<=164 MB):
//  [0,2) qh fp16 ([2,4) free)  [8,10) kh fp16  [12,14) kl fp16
//  (oatt aliases [0,8) after k_qkv)
//  [24,28) vth fp16 (hi only; written by k_proj now)
//  [33,97) A fp16    ([33,41) doubles as xh/xl before k_qkv overwrites it)
//  [97,113) Opart    [113,113.25) ml
//  [161,162.5) wth   [162.5,164) wtl
// ---------------------------------------------------------------------------
extern "C" void kernel_launch(void* const* d_in, const int* in_sizes, int n_in,
                              void* d_out, int out_size, void* d_ws, size_t ws_size,
                              hipStream_t stream)
{
  (void)in_sizes; (void)n_in; (void)out_size; (void)ws_size;
  const float* x  = (const float*)d_in[0];
  const float* wq = (const float*)d_in[1];
  const float* wk = (const float*)d_in[2];
  const float* wv = (const float*)d_in[3];
  const float* wo = (const float*)d_in[4];
  float* out = (float*)d_out;

  char* ws = (char*)d_ws;
  const size_t MB = 1024 * 1024;
  _Float16*       qh = (_Float16*)(ws);
  _Float16*       kh = (_Float16*)(ws + 8 * MB);
  _Float16*       kl = (_Float16*)(ws + 12 * MB);
  _Float16*       vth = (_Float16*)(ws + 24 * MB);
  float*          oatt = (float*)(ws);                    // aliases qh (dead)
  _Float16*       A  = (_Float16*)(ws + 33 * MB);
  unsigned short* xh = (unsigned short*)(ws + 33 * MB);   // aliases A (dead by k_qkv)
  unsigned short* xl = (unsigned short*)(ws + 37 * MB);
  float*          Opart = (float*)(ws + 97 * MB);
  float*          ml = (float*)(ws + 113 * MB);
  unsigned short* wth = (unsigned short*)(ws + 161 * MB);
  unsigned short* wtl = (unsigned short*)(ws + 161 * MB + 1536 * 1024);

  hipLaunchKernelGGL(k_prep, dim3(2048 + 192), dim3(256), 0, stream,
                     x, wq, wk, wv, xh, xl, wth, wtl);
  hipLaunchKernelGGL(k_proj_mfma, dim3(12, 64), dim3(256), 0, stream,
                     xh, xl, wth, wtl, qh, kh, kl, vth);
  hipLaunchKernelGGL(k_qkv, dim3(1088), dim3(256), 0, stream,
                     qh, kh, kl, A);
  hipLaunchKernelGGL(k_scan, dim3(512), dim3(1024), 0, stream, A);
  hipLaunchKernelGGL(k_pv, dim3(3072), dim3(64), 0, stream, A, vth,
                     oatt, Opart, ml);
  hipLaunchKernelGGL(k_oproj, dim3(64, 32), dim3(256), 0, stream,
                     oatt, wo, Opart, ml, out);
}